// Round 12
// baseline (2592.747 us; speedup 1.0000x reference)
//
#include <hip/hip_runtime.h>
#include <stdint.h>

// UniLSTM: B=64, T=512, E=1024, H=1024.
// Phase 0: f32->f16 converts + bias sum.
// Phase 1: xprojT[T][64][4096] = (x @ W_ih^T + bsum), f16, time-major (off-ring:
//          runs at ~1.2 TF effective, essentially free vs the ring period).
// Phase 2: persistent recurrence, 256 WGs x 256 thr = 4 groups x 64 unit-slices.
//   R12 = R6 verbatim (tagged u32 ping-pong exchange: data+readiness in one
//   word; proven local-opt vs R7/R9/R10 perturbations; R11's fusion regressed
//   because the ring has no absolute slack) + ONE change: the poll-gather
//   issues all 16 chunks in one flight with ONE vmcnt(0) per sweep (R6 split
//   it into two serialized 8-chunk drains) -> one fewer LLC RT per sweep.

typedef _Float16 half8 __attribute__((ext_vector_type(8)));
typedef _Float16 half4_ __attribute__((ext_vector_type(4)));
typedef float f32x4 __attribute__((ext_vector_type(4)));
typedef unsigned int u32x4 __attribute__((ext_vector_type(4)));

// ---------------- converts ----------------
__global__ void k_f32_to_f16(const float* __restrict__ s, _Float16* __restrict__ d, int n4) {
  int i = blockIdx.x * blockDim.x + threadIdx.x;
  if (i >= n4) return;
  f32x4 v = ((const f32x4*)s)[i];
  half4_ h;
  h.x = (_Float16)v.x; h.y = (_Float16)v.y; h.z = (_Float16)v.z; h.w = (_Float16)v.w;
  ((half4_*)d)[i] = h;
}

__global__ void k_bias_sum(const float* __restrict__ a, const float* __restrict__ b,
                           float* __restrict__ o) {
  int i = blockIdx.x * blockDim.x + threadIdx.x;
  if (i < 4096) o[i] = a[i] + b[i];
}

// ---------------- phase 1: input projection GEMM ----------------
// logical C[M=32768, N=4096] = X[M,1024] @ W[N,1024]^T + bsum[N], stored TIME-MAJOR:
// row = b*512+t -> written at C[(t*64 + b)*4096 + col]
__global__ __launch_bounds__(256, 2) void k_gemm_xproj(
    const _Float16* __restrict__ X, const _Float16* __restrict__ W,
    const float* __restrict__ bsum, _Float16* __restrict__ C) {
  __shared__ _Float16 As[128 * 64];
  __shared__ _Float16 Bs[128 * 64];
  const int bid = blockIdx.x;
  const int ntile = bid & 31, mtile = bid >> 5;
  const int tid = threadIdx.x;
  const int wave = tid >> 6, lane = tid & 63;
  const int wr = wave >> 1, wc = wave & 1;
  const int R0 = lane >> 3, cg = lane & 7;

  f32x4 acc[4][4];
#pragma unroll
  for (int m = 0; m < 4; m++)
#pragma unroll
    for (int n = 0; n < 4; n++) acc[m][n] = (f32x4){0.f, 0.f, 0.f, 0.f};

  for (int k0 = 0; k0 < 1024; k0 += 64) {
#pragma unroll
    for (int i = 0; i < 4; i++) {
      const int rr = (wave * 4 + i) * 8 + R0;
      const _Float16* ga = X + (size_t)(mtile * 128 + rr) * 1024 + k0 + ((cg ^ (rr & 7)) * 8);
      const _Float16* gb = W + (size_t)(ntile * 128 + rr) * 1024 + k0 + ((cg ^ (rr & 7)) * 8);
      __builtin_amdgcn_global_load_lds(
          (const __attribute__((address_space(1))) void*)ga,
          (__attribute__((address_space(3))) void*)((char*)As + (wave * 4 + i) * 1024), 16, 0, 0);
      __builtin_amdgcn_global_load_lds(
          (const __attribute__((address_space(1))) void*)gb,
          (__attribute__((address_space(3))) void*)((char*)Bs + (wave * 4 + i) * 1024), 16, 0, 0);
    }
    asm volatile("s_waitcnt vmcnt(0)" ::: "memory");
    __syncthreads();
#pragma unroll
    for (int kk = 0; kk < 2; kk++) {
      half8 af[4], bf[4];
#pragma unroll
      for (int m = 0; m < 4; m++) {
        int r = wr * 64 + m * 16 + (lane & 15);
        af[m] = *(const half8*)((const char*)As + r * 128 +
                                (((kk * 4 + (lane >> 4)) ^ (r & 7)) << 4));
      }
#pragma unroll
      for (int n = 0; n < 4; n++) {
        int r = wc * 64 + n * 16 + (lane & 15);
        bf[n] = *(const half8*)((const char*)Bs + r * 128 +
                                (((kk * 4 + (lane >> 4)) ^ (r & 7)) << 4));
      }
#pragma unroll
      for (int m = 0; m < 4; m++)
#pragma unroll
        for (int n = 0; n < 4; n++)
          acc[m][n] = __builtin_amdgcn_mfma_f32_16x16x32_f16(af[m], bf[n], acc[m][n], 0, 0, 0);
    }
    __syncthreads();
  }
#pragma unroll
  for (int n = 0; n < 4; n++) {
    int col = ntile * 128 + wc * 64 + n * 16 + (lane & 15);
    float bs = bsum[col];
#pragma unroll
    for (int m = 0; m < 4; m++)
#pragma unroll
      for (int q = 0; q < 4; q++) {
        int row = mtile * 128 + wr * 64 + m * 16 + (lane >> 4) * 4 + q;  // = b*512 + t
        int bb = row >> 9, tt = row & 511;
        C[((size_t)tt * 64 + bb) * 4096 + col] = (_Float16)(acc[m][n][q] + bs);
      }
  }
}

// ---------------- phase 2: recurrence ----------------
// WG (g, s): XCD-swizzled: g=(bid&7)>>1, s=(bid&1)*32+(bid>>3).
// Wave w = gate w; MFMA col n = unit s*16+n -> W_hh row 1024*w + s*16 + n.
// Exchange: hbuf u32[2][64][1024] ping-pong of tagged words ((t+1)<<16|h16).
// Consumer polls buf[t&1] until all tags==t; SINGLE 16-chunk flight per sweep.
__global__ __launch_bounds__(256, 1) void k_lstm_rec(
    const _Float16* __restrict__ Whh,     // [4096][1024] f16
    const _Float16* __restrict__ xprojT,  // [512][64][4096] f16 time-major
    const int* __restrict__ seqlen,       // [64]
    unsigned* __restrict__ hbuf,          // [2][64][1024] tagged u32, zeroed per launch
    float* __restrict__ out) {            // [64][1024] f32
  __shared__ _Float16 h_lds[16 * 1024];  // 32 KB packed f16, XOR-swizzled 16B slots
  __shared__ float gates[64 * 17];       // transposed [col][row], pad 17

  const int bid = blockIdx.x;
  const int x8 = bid & 7;                    // XCD (perf heuristic only)
  const int g = x8 >> 1;                     // batch group 0..3
  const int s = (x8 & 1) * 32 + (bid >> 3);  // unit slice 0..63
  const int tid = threadIdx.x;
  const int wave = tid >> 6, lane = tid & 63;

  for (int i = tid; i < 4096; i += 256) ((uint64_t*)h_lds)[i] = 0ull;  // h_0 = 0

  // W_hh B-fragments, register-resident (mapping validated R2..R11)
  half8 wfrag[32];
  {
    const _Float16* wp =
        Whh + (size_t)(1024 * wave + s * 16 + (lane & 15)) * 1024 + (lane >> 4) * 8;
#pragma unroll
    for (int kk = 0; kk < 32; kk++) wfrag[kk] = *(const half8*)(wp + kk * 32);
  }

  int Lg = 1;
  for (int b = 0; b < 16; b++) {
    int L = seqlen[g * 16 + b];
    Lg = L > Lg ? L : Lg;
  }
  const int be = tid >> 4, ue = tid & 15;  // elementwise cell (batch row, unit)
  const int mylen = seqlen[g * 16 + be];
  float c_state = 0.f;

  const int rowbase = (lane & 15) * 2048;   // A-frag row byte base
  const int xorm = ((lane & 15) & 7) << 4;  // A-frag XOR swizzle

  __syncthreads();  // h_lds zeros visible for t=0

  for (int t = 0; t < Lg; t++) {
    // xp loads (independent of h), issued before the poll-gather
    float xp[4];
#pragma unroll
    for (int q = 0; q < 4; q++) {
      int bm = (lane >> 4) * 4 + q;
      xp[q] = (float)xprojT[((size_t)t * 64 + g * 16 + bm) * 4096 + 1024 * wave + s * 16 +
                            (lane & 15)];
    }

    if (t > 0) {
      // poll-gather: ALL 16 chunks in one flight, ONE vmcnt(0) per sweep,
      // pending-only re-issue. chunk ch = tid + i*256 over [16][1024] tagged u32.
      const unsigned* src = hbuf + ((size_t)(t & 1)) * 65536 + (size_t)g * 16384;
      const unsigned Etag = (unsigned)t << 16;
      u32x4 hv[16];
#pragma unroll
      for (int i = 0; i < 16; i++) {
        asm volatile("global_load_dwordx4 %0, %1, off sc0 sc1"
                     : "=v"(hv[i]) : "v"(src + (size_t)(tid + (i << 8)) * 4) : "memory");
      }
      asm volatile("s_waitcnt vmcnt(0)" ::: "memory");
      unsigned done = 0;
      for (;;) {
#pragma unroll
        for (int i = 0; i < 16; i++) {
          if (!(done & (1u << i))) {
            unsigned m = ((hv[i].x ^ Etag) | (hv[i].y ^ Etag) | (hv[i].z ^ Etag) |
                          (hv[i].w ^ Etag)) & 0xFFFF0000u;
            if (__all(m == 0u)) done |= 1u << i;
          }
        }
        if (done == 0xFFFFu) break;
#pragma unroll
        for (int i = 0; i < 16; i++) {
          if (!(done & (1u << i))) {
            asm volatile("global_load_dwordx4 %0, %1, off sc0 sc1"
                         : "=v"(hv[i]) : "v"(src + (size_t)(tid + (i << 8)) * 4) : "memory");
          }
        }
        asm volatile("s_waitcnt vmcnt(0)" ::: "memory");
      }
      // strip tags, pack 4 u32 -> 8B f16, write swizzled LDS (R6 map)
#pragma unroll
      for (int i = 0; i < 16; i++) {
        int ch = tid + (i << 8);
        int br = ch >> 8, cidx = ch & 255;
        unsigned lo = (hv[i].x & 0xFFFFu) | (hv[i].y << 16);
        unsigned hi = (hv[i].z & 0xFFFFu) | (hv[i].w << 16);
        *(uint64_t*)((char*)h_lds + br * 2048 + (((cidx >> 1) ^ (br & 7)) << 4) +
                     (cidx & 1) * 8) = (uint64_t)lo | ((uint64_t)hi << 32);
      }
    }
    __syncthreads();  // (A) h_lds ready; also WAR-protects gates

    // gates: M=16 x N=16, K=1024 -> 32 MFMAs in 4 accumulator chains
    f32x4 a0 = (f32x4){0.f, 0.f, 0.f, 0.f};
    f32x4 a1 = (f32x4){0.f, 0.f, 0.f, 0.f};
    f32x4 a2 = (f32x4){0.f, 0.f, 0.f, 0.f};
    f32x4 a3 = (f32x4){0.f, 0.f, 0.f, 0.f};
    const char* lb = (const char*)h_lds + rowbase;
#pragma unroll
    for (int kk = 0; kk < 32; kk += 4) {
      half8 f0 = *(const half8*)(lb + ((((kk + 0) * 4 + (lane >> 4)) << 4) ^ xorm));
      half8 f1 = *(const half8*)(lb + ((((kk + 1) * 4 + (lane >> 4)) << 4) ^ xorm));
      half8 f2 = *(const half8*)(lb + ((((kk + 2) * 4 + (lane >> 4)) << 4) ^ xorm));
      half8 f3 = *(const half8*)(lb + ((((kk + 3) * 4 + (lane >> 4)) << 4) ^ xorm));
      a0 = __builtin_amdgcn_mfma_f32_16x16x32_f16(f0, wfrag[kk + 0], a0, 0, 0, 0);
      a1 = __builtin_amdgcn_mfma_f32_16x16x32_f16(f1, wfrag[kk + 1], a1, 0, 0, 0);
      a2 = __builtin_amdgcn_mfma_f32_16x16x32_f16(f2, wfrag[kk + 2], a2, 0, 0, 0);
      a3 = __builtin_amdgcn_mfma_f32_16x16x32_f16(f3, wfrag[kk + 3], a3, 0, 0, 0);
    }
    {
      f32x4 gv4;
#pragma unroll
      for (int q = 0; q < 4; q++) gv4[q] = (a0[q] + a1[q]) + (a2[q] + a3[q]) + xp[q];
      *(f32x4*)&gates[(wave * 16 + (lane & 15)) * 17 + (lane >> 4) * 4] = gv4;
    }
    __syncthreads();  // (B) gates ready

    // elementwise: thread owns (be, ue)
    float iv = gates[(0 + ue) * 17 + be];
    float fv = gates[(16 + ue) * 17 + be];
    float gv = gates[(32 + ue) * 17 + be];
    float ov = gates[(48 + ue) * 17 + be];
    iv = 1.f / (1.f + __expf(-iv));
    fv = 1.f / (1.f + __expf(-fv));
    gv = 1.f - 2.f / (1.f + __expf(2.f * gv));
    ov = 1.f / (1.f + __expf(-ov));
    c_state = fv * c_state + iv * gv;
    float tc = 1.f - 2.f / (1.f + __expf(2.f * c_state));
    float hv = ov * tc;
    if (t + 1 == mylen) out[(size_t)(g * 16 + be) * 1024 + s * 16 + ue] = hv;

    if (t + 1 < Lg) {
      _Float16 hf = (_Float16)hv;
      unsigned short hb;
      __builtin_memcpy(&hb, &hf, 2);
      unsigned tw = ((unsigned)(t + 1) << 16) | (unsigned)hb;
      __hip_atomic_store(hbuf + ((size_t)((t + 1) & 1)) * 65536 +
                             (size_t)(g * 16 + be) * 1024 + s * 16 + ue,
                         tw, __ATOMIC_RELAXED, __HIP_MEMORY_SCOPE_AGENT);
      // no drain, no flag, no barrier — readiness travels with the data
    }
  }
}

// ---------------- launch ----------------
extern "C" void kernel_launch(void* const* d_in, const int* in_sizes, int n_in, void* d_out,
                              int out_size, void* d_ws, size_t ws_size, hipStream_t stream) {
  const float* emb = (const float*)d_in[0];   // [64,512,1024]
  const int* slen = (const int*)d_in[1];      // [64]
  const float* Wih = (const float*)d_in[2];   // [4096,1024]
  const float* Whh = (const float*)d_in[3];   // [4096,1024]
  const float* bih = (const float*)d_in[4];   // [4096]
  const float* bhh = (const float*)d_in[5];   // [4096]
  float* out = (float*)d_out;

  char* ws = (char*)d_ws;
  _Float16* xprojT = (_Float16*)(ws + 0);        // 268,435,456 B [512][64][4096]
  _Float16* xf = (_Float16*)(ws + 268435456);    //  67,108,864 B (dead after GEMM)
  unsigned* hbuf = (unsigned*)(ws + 268435456);  //     524,288 B [2][64][1024] u32 (aliases xf)
  _Float16* wihf = (_Float16*)(ws + 335544320);  //   8,388,608 B
  _Float16* whhf = (_Float16*)(ws + 343932928);  //   8,388,608 B
  float* bsum = (float*)(ws + 352321536);        //      16,384 B
  // total ws use: 352,337,920 B

  k_f32_to_f16<<<(8388608 + 255) / 256, 256, 0, stream>>>(emb, xf, 8388608);
  k_f32_to_f16<<<(1048576 + 255) / 256, 256, 0, stream>>>(Wih, wihf, 1048576);
  k_f32_to_f16<<<(1048576 + 255) / 256, 256, 0, stream>>>(Whh, whhf, 1048576);
  k_bias_sum<<<16, 256, 0, stream>>>(bih, bhh, bsum);
  k_gemm_xproj<<<8192, 256, 0, stream>>>(xf, wihf, bsum, xprojT);
  // zero ALL tags AFTER the GEMM consumed xf (hbuf aliases xf); tag 0 never polled
  hipMemsetAsync(hbuf, 0, 524288, stream);
  k_lstm_rec<<<256, 256, 0, stream>>>(whhf, xprojT, slen, hbuf, out);
}

// Round 13
// 1944.859 us; speedup vs baseline: 1.3331x; 1.3331x over previous
//
#include <hip/hip_runtime.h>
#include <stdint.h>

// UniLSTM: B=64, T=512, E=1024, H=1024.
// R13 = byte-exact revert to R6, the measured optimum of this session
// (total 1948us; rec 1650us). R7-R12 perturbed every dimension of the
// exchange (consumers, bytes, requests, sweep structure, fusion) and ALL
// regressed => R6's tagged u32 ping-pong at 256WGx256thr is a sharp local
// optimum; the ring is sync-latency bound (~3.2us/step = store-visibility +
// 1-2 poll RTs + compute), not traffic-bound.
//
// Phase 0: f32->f16 converts + bias sum.
// Phase 1: xprojT[T][64][4096] = (x @ W_ih^T + bsum), f16, time-major.
// Phase 2: persistent recurrence, 256 WGs x 256 thr = 4 groups x 64 unit-slices.
//   Tagged ping-pong h exchange: h stored as ((t+1)<<16|h_f16) u32 in an
//   LLC-resident ping-pong buffer; the gather IS the poll (validate 4 tags
//   per 16B chunk, re-read only pending chunks). Producer has NO drain, NO
//   flag, NO trailing barrier - readiness travels with the data.

typedef _Float16 half8 __attribute__((ext_vector_type(8)));
typedef _Float16 half4_ __attribute__((ext_vector_type(4)));
typedef float f32x4 __attribute__((ext_vector_type(4)));
typedef unsigned int u32x4 __attribute__((ext_vector_type(4)));

#define T_SEQ 512

// ---------------- converts ----------------
__global__ void k_f32_to_f16(const float* __restrict__ s, _Float16* __restrict__ d, int n4) {
  int i = blockIdx.x * blockDim.x + threadIdx.x;
  if (i >= n4) return;
  f32x4 v = ((const f32x4*)s)[i];
  half4_ h;
  h.x = (_Float16)v.x; h.y = (_Float16)v.y; h.z = (_Float16)v.z; h.w = (_Float16)v.w;
  ((half4_*)d)[i] = h;
}

__global__ void k_bias_sum(const float* __restrict__ a, const float* __restrict__ b,
                           float* __restrict__ o) {
  int i = blockIdx.x * blockDim.x + threadIdx.x;
  if (i < 4096) o[i] = a[i] + b[i];
}

// ---------------- phase 1: input projection GEMM ----------------
// logical C[M=32768, N=4096] = X[M,1024] @ W[N,1024]^T + bsum[N], stored TIME-MAJOR:
// row = b*512+t -> written at C[(t*64 + b)*4096 + col]
__global__ __launch_bounds__(256, 2) void k_gemm_xproj(
    const _Float16* __restrict__ X, const _Float16* __restrict__ W,
    const float* __restrict__ bsum, _Float16* __restrict__ C) {
  __shared__ _Float16 As[128 * 64];
  __shared__ _Float16 Bs[128 * 64];
  const int bid = blockIdx.x;
  const int ntile = bid & 31, mtile = bid >> 5;
  const int tid = threadIdx.x;
  const int wave = tid >> 6, lane = tid & 63;
  const int wr = wave >> 1, wc = wave & 1;
  const int R0 = lane >> 3, cg = lane & 7;

  f32x4 acc[4][4];
#pragma unroll
  for (int m = 0; m < 4; m++)
#pragma unroll
    for (int n = 0; n < 4; n++) acc[m][n] = (f32x4){0.f, 0.f, 0.f, 0.f};

  for (int k0 = 0; k0 < 1024; k0 += 64) {
#pragma unroll
    for (int i = 0; i < 4; i++) {
      const int rr = (wave * 4 + i) * 8 + R0;
      const _Float16* ga = X + (size_t)(mtile * 128 + rr) * 1024 + k0 + ((cg ^ (rr & 7)) * 8);
      const _Float16* gb = W + (size_t)(ntile * 128 + rr) * 1024 + k0 + ((cg ^ (rr & 7)) * 8);
      __builtin_amdgcn_global_load_lds(
          (const __attribute__((address_space(1))) void*)ga,
          (__attribute__((address_space(3))) void*)((char*)As + (wave * 4 + i) * 1024), 16, 0, 0);
      __builtin_amdgcn_global_load_lds(
          (const __attribute__((address_space(1))) void*)gb,
          (__attribute__((address_space(3))) void*)((char*)Bs + (wave * 4 + i) * 1024), 16, 0, 0);
    }
    asm volatile("s_waitcnt vmcnt(0)" ::: "memory");
    __syncthreads();
#pragma unroll
    for (int kk = 0; kk < 2; kk++) {
      half8 af[4], bf[4];
#pragma unroll
      for (int m = 0; m < 4; m++) {
        int r = wr * 64 + m * 16 + (lane & 15);
        af[m] = *(const half8*)((const char*)As + r * 128 +
                                (((kk * 4 + (lane >> 4)) ^ (r & 7)) << 4));
      }
#pragma unroll
      for (int n = 0; n < 4; n++) {
        int r = wc * 64 + n * 16 + (lane & 15);
        bf[n] = *(const half8*)((const char*)Bs + r * 128 +
                                (((kk * 4 + (lane >> 4)) ^ (r & 7)) << 4));
      }
#pragma unroll
      for (int m = 0; m < 4; m++)
#pragma unroll
        for (int n = 0; n < 4; n++)
          acc[m][n] = __builtin_amdgcn_mfma_f32_16x16x32_f16(af[m], bf[n], acc[m][n], 0, 0, 0);
    }
    __syncthreads();
  }
#pragma unroll
  for (int n = 0; n < 4; n++) {
    int col = ntile * 128 + wc * 64 + n * 16 + (lane & 15);
    float bs = bsum[col];
#pragma unroll
    for (int m = 0; m < 4; m++)
#pragma unroll
      for (int q = 0; q < 4; q++) {
        int row = mtile * 128 + wr * 64 + m * 16 + (lane >> 4) * 4 + q;  // = b*512 + t
        int bb = row >> 9, tt = row & 511;
        C[((size_t)tt * 64 + bb) * 4096 + col] = (_Float16)(acc[m][n][q] + bs);
      }
  }
}

// ---------------- phase 2: recurrence ----------------
// WG (g, s): XCD-swizzled (perf-only): g=(bid&7)>>1, s=(bid&1)*32+(bid>>3).
// Wave w = gate w; MFMA col n = unit s*16+n -> W_hh row 1024*w + s*16 + n.
// Exchange: hbuf u32[2][64][1024] ping-pong of tagged words ((t+1)<<16|h16).
// Consumer polls buf[t&1] until every chunk's 4 tags == t; pending-only rereads.
__global__ __launch_bounds__(256, 1) void k_lstm_rec(
    const _Float16* __restrict__ Whh,     // [4096][1024] f16
    const _Float16* __restrict__ xprojT,  // [512][64][4096] f16 time-major
    const int* __restrict__ seqlen,       // [64]
    unsigned* __restrict__ hbuf,          // [2][64][1024] tagged u32, zeroed per launch
    float* __restrict__ out) {            // [64][1024] f32
  __shared__ _Float16 h_lds[16 * 1024];  // 32 KB packed f16, XOR-swizzled 16B chunks
  __shared__ float gates[64 * 17];       // transposed [col][row], pad 17

  const int bid = blockIdx.x;
  const int x8 = bid & 7;                    // XCD (perf heuristic only)
  const int g = x8 >> 1;                     // batch group 0..3
  const int s = (x8 & 1) * 32 + (bid >> 3);  // unit slice 0..63
  const int tid = threadIdx.x;
  const int wave = tid >> 6, lane = tid & 63;

  for (int i = tid; i < 4096; i += 256) ((uint64_t*)h_lds)[i] = 0ull;  // h_0 = 0

  // W_hh B-fragments, register-resident (mapping validated R2/R5)
  half8 wfrag[32];
  {
    const _Float16* wp =
        Whh + (size_t)(1024 * wave + s * 16 + (lane & 15)) * 1024 + (lane >> 4) * 8;
#pragma unroll
    for (int kk = 0; kk < 32; kk++) wfrag[kk] = *(const half8*)(wp + kk * 32);
  }

  int Lg = 1;
  for (int b = 0; b < 16; b++) {
    int L = seqlen[g * 16 + b];
    Lg = L > Lg ? L : Lg;
  }
  const int be = tid >> 4, ue = tid & 15;  // elementwise cell (batch row, unit)
  const int mylen = seqlen[g * 16 + be];
  float c_state = 0.f;

  const int rowbase = (lane & 15) * 2048;   // A-frag row byte base
  const int xorm = ((lane & 15) & 7) << 4;  // A-frag XOR swizzle

  __syncthreads();  // h_lds zeros visible for t=0

  for (int t = 0; t < Lg; t++) {
    // xp loads (independent of h), issued before the poll-gather
    float xp[4];
#pragma unroll
    for (int q = 0; q < 4; q++) {
      int bm = (lane >> 4) * 4 + q;
      xp[q] = (float)xprojT[((size_t)t * 64 + g * 16 + bm) * 4096 + 1024 * wave + s * 16 +
                            (lane & 15)];
    }

    if (t > 0) {
      // poll-gather: 16 sweeps-chunks/thread over [16][1024] tagged u32 (64KB/WG).
      // chunk ch = tid + idx*256 -> row = idx (whole WG loads one row per idx).
      const unsigned* src = hbuf + ((size_t)(t & 1)) * 65536 + (size_t)g * 16384;
      const unsigned Etag = (unsigned)t << 16;
#pragma unroll
      for (int hf = 0; hf < 2; hf++) {  // two halves of 8 chunks (VGPR cap)
        u32x4 hv[8];
        unsigned done = 0;
        while (done != 0xFFu) {
#pragma unroll
          for (int i = 0; i < 8; i++) {
            if (!(done & (1u << i))) {
              asm volatile("global_load_dwordx4 %0, %1, off sc0 sc1"
                           : "=v"(hv[i])
                           : "v"(src + (size_t)(tid + ((hf * 8 + i) << 8)) * 4)
                           : "memory");
            }
          }
          asm volatile("s_waitcnt vmcnt(0)" ::: "memory");
#pragma unroll
          for (int i = 0; i < 8; i++) {
            if (!(done & (1u << i))) {
              unsigned m = ((hv[i].x ^ Etag) | (hv[i].y ^ Etag) | (hv[i].z ^ Etag) |
                            (hv[i].w ^ Etag)) & 0xFFFF0000u;
              if (__all(m == 0u)) done |= 1u << i;
            }
          }
        }
        // strip tags, pack 4 u32 -> 8B f16, write swizzled LDS
#pragma unroll
        for (int i = 0; i < 8; i++) {
          int ch = tid + ((hf * 8 + i) << 8);
          int br = ch >> 8, cidx = ch & 255;
          unsigned lo = (hv[i].x & 0xFFFFu) | (hv[i].y << 16);
          unsigned hi = (hv[i].z & 0xFFFFu) | (hv[i].w << 16);
          *(uint64_t*)((char*)h_lds + br * 2048 + (((cidx >> 1) ^ (br & 7)) << 4) +
                       (cidx & 1) * 8) = (uint64_t)lo | ((uint64_t)hi << 32);
        }
      }
    }
    __syncthreads();  // (A) h_lds ready; also WAR-protects gates

    // gates: M=16 x N=16, K=1024 -> 32 MFMAs in 4 accumulator chains
    f32x4 a0 = (f32x4){0.f, 0.f, 0.f, 0.f};
    f32x4 a1 = (f32x4){0.f, 0.f, 0.f, 0.f};
    f32x4 a2 = (f32x4){0.f, 0.f, 0.f, 0.f};
    f32x4 a3 = (f32x4){0.f, 0.f, 0.f, 0.f};
    const char* lb = (const char*)h_lds + rowbase;
#pragma unroll
    for (int kk = 0; kk < 32; kk += 4) {
      half8 f0 = *(const half8*)(lb + ((((kk + 0) * 4 + (lane >> 4)) << 4) ^ xorm));
      half8 f1 = *(const half8*)(lb + ((((kk + 1) * 4 + (lane >> 4)) << 4) ^ xorm));
      half8 f2 = *(const half8*)(lb + ((((kk + 2) * 4 + (lane >> 4)) << 4) ^ xorm));
      half8 f3 = *(const half8*)(lb + ((((kk + 3) * 4 + (lane >> 4)) << 4) ^ xorm));
      a0 = __builtin_amdgcn_mfma_f32_16x16x32_f16(f0, wfrag[kk + 0], a0, 0, 0, 0);
      a1 = __builtin_amdgcn_mfma_f32_16x16x32_f16(f1, wfrag[kk + 1], a1, 0, 0, 0);
      a2 = __builtin_amdgcn_mfma_f32_16x16x32_f16(f2, wfrag[kk + 2], a2, 0, 0, 0);
      a3 = __builtin_amdgcn_mfma_f32_16x16x32_f16(f3, wfrag[kk + 3], a3, 0, 0, 0);
    }
    {
      f32x4 gv4;
#pragma unroll
      for (int q = 0; q < 4; q++) gv4[q] = (a0[q] + a1[q]) + (a2[q] + a3[q]) + xp[q];
      *(f32x4*)&gates[(wave * 16 + (lane & 15)) * 17 + (lane >> 4) * 4] = gv4;
    }
    __syncthreads();  // (B) gates ready

    // elementwise: thread owns (be, ue)
    float iv = gates[(0 + ue) * 17 + be];
    float fv = gates[(16 + ue) * 17 + be];
    float gv = gates[(32 + ue) * 17 + be];
    float ov = gates[(48 + ue) * 17 + be];
    iv = 1.f / (1.f + __expf(-iv));
    fv = 1.f / (1.f + __expf(-fv));
    gv = 1.f - 2.f / (1.f + __expf(2.f * gv));
    ov = 1.f / (1.f + __expf(-ov));
    c_state = fv * c_state + iv * gv;
    float tc = 1.f - 2.f / (1.f + __expf(2.f * c_state));
    float hv = ov * tc;
    if (t + 1 == mylen) out[(size_t)(g * 16 + be) * 1024 + s * 16 + ue] = hv;

    if (t + 1 < Lg) {
      _Float16 hfv = (_Float16)hv;
      unsigned short hb;
      __builtin_memcpy(&hb, &hfv, 2);
      unsigned tw = ((unsigned)(t + 1) << 16) | (unsigned)hb;
      // tagged store: 16 lanes x 4B = 64B full-sector, LLC-resident ping-pong
      __hip_atomic_store(hbuf + ((size_t)((t + 1) & 1)) * 65536 +
                             (size_t)(g * 16 + be) * 1024 + s * 16 + ue,
                         tw, __ATOMIC_RELAXED, __HIP_MEMORY_SCOPE_AGENT);
      // no drain, no flag, no barrier — readiness travels with the data
    }
  }
}

// ---------------- launch ----------------
extern "C" void kernel_launch(void* const* d_in, const int* in_sizes, int n_in, void* d_out,
                              int out_size, void* d_ws, size_t ws_size, hipStream_t stream) {
  const float* emb = (const float*)d_in[0];   // [64,512,1024]
  const int* slen = (const int*)d_in[1];      // [64]
  const float* Wih = (const float*)d_in[2];   // [4096,1024]
  const float* Whh = (const float*)d_in[3];   // [4096,1024]
  const float* bih = (const float*)d_in[4];   // [4096]
  const float* bhh = (const float*)d_in[5];   // [4096]
  float* out = (float*)d_out;

  char* ws = (char*)d_ws;
  _Float16* xprojT = (_Float16*)(ws + 0);        // 268,435,456 B [512][64][4096]
  _Float16* xf = (_Float16*)(ws + 268435456);    //  67,108,864 B (dead after GEMM)
  unsigned* hbuf = (unsigned*)(ws + 268435456);  //     524,288 B [2][64][1024] u32 (aliases xf)
  _Float16* wihf = (_Float16*)(ws + 335544320);  //   8,388,608 B
  _Float16* whhf = (_Float16*)(ws + 343932928);  //   8,388,608 B
  float* bsum = (float*)(ws + 352321536);        //      16,384 B
  // total ws use: 352,337,920 B

  k_f32_to_f16<<<(8388608 + 255) / 256, 256, 0, stream>>>(emb, xf, 8388608);
  k_f32_to_f16<<<(1048576 + 255) / 256, 256, 0, stream>>>(Wih, wihf, 1048576);
  k_f32_to_f16<<<(1048576 + 255) / 256, 256, 0, stream>>>(Whh, whhf, 1048576);
  k_bias_sum<<<16, 256, 0, stream>>>(bih, bhh, bsum);
  k_gemm_xproj<<<8192, 256, 0, stream>>>(xf, wihf, bsum, xprojT);
  // zero ALL tags AFTER the GEMM consumed xf (hbuf aliases xf); tag 0 never polled
  hipMemsetAsync(hbuf, 0, 524288, stream);
  k_lstm_rec<<<256, 256, 0, stream>>>(whhf, xprojT, slen, hbuf, out);
}